// Round 3
// baseline (358.348 us; speedup 1.0000x reference)
//
#include <hip/hip_runtime.h>
#include <cmath>

#define NB 4
#define NN 8192
#define CH 32

typedef short short8 __attribute__((ext_vector_type(8)));
typedef float floatx4 __attribute__((ext_vector_type(4)));
typedef unsigned short ushort_t;

// ---------- helpers ----------
__device__ __forceinline__ unsigned short f2b(float f){
  unsigned u = __float_as_uint(f);
  u = u + 0x7FFFu + ((u >> 16) & 1u);   // RNE
  return (unsigned short)(u >> 16);
}
__device__ __forceinline__ float b2f(unsigned short h){
  return __uint_as_float(((unsigned)h) << 16);
}
__device__ __forceinline__ float gelu_f(float v){
  return 0.5f * v * (1.0f + erff(v * 0.70710678118654752440f));
}
// rep-index closed forms (t in [0,552), t = j*24+i)
__device__ __forceinline__ int repk(int t){   // -1 if t is not a representative
  int j = t / 24, i = t - j * 24;
  if(j == 0)  return (i <= 12) ? i : -1;
  if(j <= 11) return 13 + (j - 1) * 24 + i;
  return (i == 12) ? 277 + (j - 12) : -1;
}
__device__ __forceinline__ int partner(int t){
  int j = t / 24, i = t - j * 24;
  return ((23 - j) % 23) * 24 + ((24 - i) % 24);
}
__device__ __forceinline__ int repT(int k){   // inverse of repk over reps
  if(k < 13) return k;
  if(k < 277){ int m = k - 13; return (m / 24 + 1) * 24 + (m % 24); }
  return (k - 277 + 12) * 24 + 12;
}

// ---------- fused: spec_w reorder (blocks 128..4735) + minmax partials (blocks <128)
// ---------- + fc1_w hi/lo B-fragment pre-split (block 4736) ----------
__global__ __launch_bounds__(256) void k_pre(const float* __restrict__ spec,
    float2* __restrict__ wt, const float* __restrict__ x, float4* __restrict__ pmm,
    const float* __restrict__ fc1w, ushort_t* __restrict__ WB)
{
  const int tid = threadIdx.x;
  if(blockIdx.x < 128){
    int g = blockIdx.x * 256 + tid;           // 32768 threads
    float a = x[(size_t)g * 2], b = x[(size_t)g * 2 + 1];
    float mn0 = a, mx0 = a, mn1 = b, mx1 = b;
    for(int off = 32; off > 0; off >>= 1){
      mn0 = fminf(mn0, __shfl_down(mn0, off));
      mx0 = fmaxf(mx0, __shfl_down(mx0, off));
      mn1 = fminf(mn1, __shfl_down(mn1, off));
      mx1 = fmaxf(mx1, __shfl_down(mx1, off));
    }
    __shared__ float4 wp[4];
    if((tid & 63) == 0) wp[tid >> 6] = make_float4(mn0, mn1, mx0, mx1);
    __syncthreads();
    if(tid == 0){
      float4 r = wp[0];
      for(int i2 = 1; i2 < 4; ++i2){
        float4 v = wp[i2];
        r.x = fminf(r.x, v.x); r.y = fminf(r.y, v.y);
        r.z = fmaxf(r.z, v.z); r.w = fmaxf(r.w, v.w);
      }
      pmm[blockIdx.x] = r;
    }
  } else if(blockIdx.x < 4736){
    int g = (blockIdx.x - 128) * 256 + tid;   // 1,179,648
    int o  = g & 31;
    int i  = (g >> 5) & 31;
    int rest = g >> 10;
    int pq = rest % 144;
    int ls = rest / 144;                      // l*2+sel
    wt[g] = ((const float2*)spec)[(((size_t)(ls * 32 + i) * 32 + o) * 144 + pq)];
  } else {
    // fc1_w [32][128] -> bf16 hi/lo MFMA B-fragments, 8 jj-tiles.
    for(int s = tid; s < 512; s += 256){
      int jt = s >> 6, l = s & 63;
      int c = l & 15, qq = l >> 4;
      #pragma unroll
      for(int e = 0; e < 8; ++e){
        float wv = fc1w[(qq * 8 + e) * 128 + jt * 16 + c];
        ushort_t hi = f2b(wv);
        WB[(jt * 64 + l) * 8 + e] = hi;
        WB[4096 + (jt * 64 + l) * 8 + e] = f2b(wv - b2f(hi));
      }
    }
  }
}

// ---------- build V in MFMA-fragment layouts + fc0 ----------
// AF : forward A-operand.  [b][st=36][ng=256][q=4][srow=16][e=8] shorts
// VTF: inverse B-operand.  [b][n16=512][kk=18][q=4][n15=16][e=8] shorts
__global__ __launch_bounds__(256) void k_vbuild(const float* __restrict__ x,
    const float4* __restrict__ pmm, const float* __restrict__ fw,
    const float* __restrict__ fb, ushort_t* __restrict__ AF, ushort_t* __restrict__ VTF,
    float* __restrict__ h, ushort_t* __restrict__ hb)
{
  __shared__ ushort_t lds1[32 * 584];
  __shared__ float4 mmv;
  const int tid = threadIdx.x;
  if(tid < 64){
    float4 a = pmm[tid], c = pmm[tid + 64];
    float mn0 = fminf(a.x, c.x), mn1 = fminf(a.y, c.y);
    float mx0 = fmaxf(a.z, c.z), mx1 = fmaxf(a.w, c.w);
    for(int off = 32; off > 0; off >>= 1){
      mn0 = fminf(mn0, __shfl_down(mn0, off));
      mn1 = fminf(mn1, __shfl_down(mn1, off));
      mx0 = fmaxf(mx0, __shfl_down(mx0, off));
      mx1 = fmaxf(mx1, __shfl_down(mx1, off));
    }
    if(tid == 0) mmv = make_float4(mn0, mn1, mx0, mx1);
  }
  __syncthreads();
  const int nl = tid & 31, part = tid >> 5;
  const int b = blockIdx.x >> 8;
  const int nblk = blockIdx.x & 255;
  const int n = nblk * 32 + nl;
  float mn0 = mmv.x, mn1 = mmv.y, mx0 = mmv.z, mx1 = mmv.w;
  float x0 = x[(size_t)(b * NN + n) * 2]     - mn0;
  float x1 = x[(size_t)(b * NN + n) * 2 + 1] - mn1;
  float sp = x0 * (6.28f / (mx0 - mn0));
  float sq = x1 * (6.28f / (mx1 - mn1));
  float cx, sx, cy, sy;
  sincosf(sp, &sx, &cx);
  sincosf(sq, &sy, &cy);
  int j0 = part * 3;
  int j1 = (j0 + 3 < 23) ? j0 + 3 : 23;
  float ky0 = (j0 < 12) ? (float)j0 : (float)(j0 - 23);
  float cb, sb;
  sincosf(ky0 * sq, &sb, &cb);
  for(int j = j0; j < j1; ++j){
    float ca = 1.0f, sa = 0.0f;   // kx = 0
    #pragma unroll
    for(int i = 0; i < 24; ++i){
      float vr = ca * cb - sa * sb;        //  cos(kx*sp + ky*sq)
      float vi = -(sa * cb + ca * sb);     // -sin(kx*sp + ky*sq)
      int t = j * 24 + i;
      int k = repk(t);
      if(k >= 0){
        lds1[nl * 584 + k]       = f2b(vr);
        lds1[nl * 584 + 288 + k] = f2b(vi);
      }
      float cn = ca * cx - sa * sx;
      float sn = sa * cx + ca * sx;
      if(i == 11) sn = -sn;                // kx 11 -> -12 (conjugate)
      ca = cn; sa = sn;
    }
    float cbn = cb * cy - sb * sy;
    float sbn = sb * cy + cb * sy;
    cb = cbn; sb = sbn;
  }
  __syncthreads();
  // phase-1 emission: VTF (coalesced 16B/lane)
  #pragma unroll
  for(int r = 0; r < 9; ++r){
    int c = tid + 256 * r;                  // [0,2304)
    int t16 = c / 1152;
    int c2 = c - t16 * 1152;
    int kk = c2 >> 6;
    int rem = c2 & 63;
    int q = rem >> 4, n15 = rem & 15;
    short8 v = *(const short8*)(lds1 + (t16 * 16 + n15) * 584 + kk * 32 + q * 8);
    *(short8*)(VTF + ((size_t)((b * 512 + nblk * 2 + t16) * 18 + kk)) * 512
               + (q * 16 + n15) * 8) = v;
  }
  // phase-2 emission: AF via conjugate symmetry from LDS
  #pragma unroll
  for(int r = 0; r < 9; ++r){
    int c = tid + 256 * r;                  // [0,2304)
    int st = c >> 6;
    int rem = c & 63;
    int q = rem >> 4, srow = rem & 15;
    int sg = st * 16 + srow;                // [0,576)
    int s = (sg < 288) ? sg : sg - 288;
    int sinh_ = (sg >= 288);
    int p2 = s / 12, qq = s - p2 * 12;
    int t = p2 * 23 + qq;
    int k = repk(t);
    unsigned short flip = 0;
    if(k < 0){ k = repk(partner(t)); if(sinh_) flip = 0x8000; }
    int col = sinh_ ? 288 + k : k;
    ushort_t tmp[8];
    #pragma unroll
    for(int e = 0; e < 8; ++e)
      tmp[e] = lds1[(q * 8 + e) * 584 + col] ^ flip;
    *(short8*)(AF + ((size_t)((b * 36 + st) * 256 + nblk)) * 512
               + (q * 16 + srow) * 8) = *(short8*)tmp;
  }
  // fused fc0
  #pragma unroll
  for(int rr = 0; rr < 4; ++rr){
    int c2 = (tid >> 5) + rr * 8;
    float v = fb[c2] + x0 * fw[c2] + x1 * fw[32 + c2];
    size_t idx = (size_t)(b * CH + c2) * NN + n;
    h[idx] = v; hb[idx] = f2b(v);
  }
}

// ---------- forward transform (K-split 8, 2 s-tiles/block): xp[ks][b][576][32] ----------
__global__ __launch_bounds__(256) void k_fwd(const ushort_t* __restrict__ AF,
    const ushort_t* __restrict__ hb, float* __restrict__ xp)
{
  const int stp = blockIdx.x;      // 18 pairs
  const int ks = blockIdx.y;       // 8
  const int b  = blockIdx.z;
  const int w = threadIdx.x >> 6;
  const int lane = threadIdx.x & 63;
  const int row = lane & 15;
  const int q = lane >> 4;
  const int st0 = stp * 2;
  const size_t abase0 = ((size_t)(b * 36 + st0) * 256) * 512 + (q * 16 + row) * 8;
  const size_t abase1 = abase0 + (size_t)256 * 512;
  const size_t hb0 = (size_t)(b * CH + row) * NN;
  const size_t hb1 = hb0 + (size_t)16 * NN;
  floatx4 aA0 = {0.f,0.f,0.f,0.f}, aA1 = {0.f,0.f,0.f,0.f};
  floatx4 aB0 = {0.f,0.f,0.f,0.f}, aB1 = {0.f,0.f,0.f,0.f};
  #pragma unroll
  for(int kk = 0; kk < 8; ++kk){
    int g = ks * 32 + w * 8 + kk;
    short8 A0 = *(const short8*)(AF + abase0 + (size_t)g * 512);
    short8 A1 = *(const short8*)(AF + abase1 + (size_t)g * 512);
    int nn2 = g * 32 + q * 8;
    short8 B0 = *(const short8*)(hb + hb0 + nn2);
    short8 B1 = *(const short8*)(hb + hb1 + nn2);
    aA0 = __builtin_amdgcn_mfma_f32_16x16x32_bf16(A0, B0, aA0, 0, 0, 0);
    aA1 = __builtin_amdgcn_mfma_f32_16x16x32_bf16(A0, B1, aA1, 0, 0, 0);
    aB0 = __builtin_amdgcn_mfma_f32_16x16x32_bf16(A1, B0, aB0, 0, 0, 0);
    aB1 = __builtin_amdgcn_mfma_f32_16x16x32_bf16(A1, B1, aB1, 0, 0, 0);
  }
  __shared__ float red[4 * 512];
  const int e = threadIdx.x;
  #pragma unroll
  for(int r = 0; r < 4; ++r){
    int rrow = q * 4 + r;
    red[w * 512 + rrow * 32 + row]      = aA0[r];
    red[w * 512 + rrow * 32 + 16 + row] = aA1[r];
  }
  __syncthreads();
  {
    float v0 = red[e] + red[512 + e] + red[1024 + e] + red[1536 + e];
    float v1 = red[e + 256] + red[512 + e + 256] + red[1024 + e + 256] + red[1536 + e + 256];
    size_t base = ((size_t)(ks * NB + b) * 576 + st0 * 16) * 32;
    xp[base + e] = v0;
    xp[base + e + 256] = v1;
  }
  __syncthreads();
  #pragma unroll
  for(int r = 0; r < 4; ++r){
    int rrow = q * 4 + r;
    red[w * 512 + rrow * 32 + row]      = aB0[r];
    red[w * 512 + rrow * 32 + 16 + row] = aB1[r];
  }
  __syncthreads();
  {
    float v0 = red[e] + red[512 + e] + red[1024 + e] + red[1536 + e];
    float v1 = red[e + 256] + red[512 + e + 256] + red[1024 + e + 256] + red[1536 + e + 256];
    size_t base = ((size_t)(ks * NB + b) * 576 + (st0 + 1) * 16) * 32;
    xp[base + e] = v0;
    xp[base + e + 256] = v1;
  }
}

// ---------- fused mix + fold -> ghi/glo in A-FRAGMENT layout ----------
// ghi/glo per b: [kk=18][half=2][lane=64][e=8] shorts; value (ch,p) at
// (p>>5)*1024 + (ch>>4)*512 + (((p>>3)&3)*16 + (ch&15))*8 + (p&7)
__global__ __launch_bounds__(256) void k_mixg(const float* __restrict__ xp,
    const float2* __restrict__ wt, ushort_t* __restrict__ ghi, ushort_t* __restrict__ glo,
    int layer)
{
  const int w = threadIdx.x >> 6;
  const int lane = threadIdx.x & 63;
  const int k = blockIdx.x * 4 + w;    // 288 reps
  const int b = blockIdx.y;
  const int t = repT(k);
  const int j = t / 24, i = t - j * 24;
  const int u = partner(t);
  const bool unpaired = (i == 12) || (u == t);
  const int idxT = (t < 288) ? t : 575 - t;  const bool cfT = (t >= 288);
  const int idxU = (u < 288) ? u : 575 - u;  const bool cfU = (u >= 288);
  __shared__ float Xs[4][2][64];
  const int o = lane & 31, half = lane >> 5;
  #pragma unroll
  for(int m = 0; m < 2; ++m){
    int idx = m ? idxU : idxT;
    int rrow = half ? 288 + idx : idx;
    float s = 0.f;
    #pragma unroll
    for(int ks = 0; ks < 8; ++ks)
      s += xp[((size_t)(ks * NB + b) * 576 + rrow) * 32 + o];
    Xs[w][m][half * 32 + o] = s;
  }
  __syncthreads();
  float Fr[2], Fi[2];
  #pragma unroll
  for(int m = 0; m < 2; ++m){
    int idx = m ? idxU : idxT;
    int p2 = idx / 12, qq = idx - p2 * 12;
    int sel = (p2 < 12) ? 0 : 1;
    int pq = (p2 % 12) * 12 + qq;
    const float2* wb = wt + ((size_t)((layer * 2 + sel) * 144 + pq)) * 1024;
    int i0 = half * 16;
    float fr = 0.f, fi = 0.f;
    #pragma unroll
    for(int ii = 0; ii < 16; ++ii){
      int i2 = i0 + ii;
      float xr = Xs[w][m][i2], xi = Xs[w][m][32 + i2];
      float2 wv = wb[i2 * 32 + o];
      fr += xr * wv.x - xi * wv.y;
      fi += xr * wv.y + xi * wv.x;
    }
    fr += __shfl_down(fr, 32);
    fi += __shfl_down(fi, 32);
    Fr[m] = fr; Fi[m] = fi;       // valid in lanes 0..31
  }
  const int c = lane & 31;
  const int srcT = cfT ? 31 - c : c;
  const int srcU = cfU ? 31 - c : c;
  float fax = __shfl(Fr[0], srcT);
  float fay = __shfl(Fi[0], srcT);
  float fbx = __shfl(Fr[1], srcU);
  float fby = __shfl(Fi[1], srcU);
  if(lane < 32){
    float gr = fax;
    float gi = cfT ? -fay : fay;
    if(!unpaired){
      gr += fbx;
      gi -= (cfU ? -fby : fby);
    }
    unsigned short hr = f2b(gr); float lr = gr - b2f(hr);
    unsigned short hi2 = f2b(gi); float li = gi - b2f(hi2);
    const size_t base = (size_t)b * 18432;
    // p = k (real part), p = 288 + k (imag part; 288 = 9*32 -> +9*1024)
    int A1 = (k >> 5) * 1024 + ((c >> 4) << 9)
           + ((((k >> 3) & 3) << 4) + (c & 15)) * 8 + (k & 7);
    int A2 = A1 + 9 * 1024;
    ghi[base + A1] = hr;          ghi[base + A2] = hi2;
    glo[base + A1] = f2b(lr);     glo[base + A2] = f2b(li);
  }
}

// ---------- inverse transform + fused 1x1 conv (+gelu | +MFMA fc1/fc2 epilogue) ----------
// 256 threads = 4 waves, 32 points/block, grid (256,NB) = 1024 blocks -> 4 blocks/CU.
// No LDS staging of G: A-fragments (ghi/glo) read straight from L2-resident global,
// 1 KB/wave contiguous per fragment. kk split 2-ways across wave pairs (9 each),
// cross-wave combine via 4 KB LDS exchange. Main loop has NO barrier.
template<int LAST>
__global__ __launch_bounds__(256, 4) void k_inv(const ushort_t* __restrict__ VTF,
    const ushort_t* __restrict__ ghi, const ushort_t* __restrict__ glo,
    const float* __restrict__ hfull, const float* __restrict__ cw,
    const float* __restrict__ cbias, float* __restrict__ hout,
    ushort_t* __restrict__ houtb, int layer,
    const float* __restrict__ w1, const float* __restrict__ b1,
    const float* __restrict__ w2, const float* __restrict__ b2,
    float* __restrict__ out, const ushort_t* __restrict__ WBg)
{
  __shared__ floatx4 xch[4][64];     // cross-wave partial exchange
  __shared__ float hTc[32][33];      // conv input tile [ch][pt 0..31]
  __shared__ float Wl[1024];         // transposed conv W: Wl[i*32+o]
  __shared__ float Bl[32];
  const int tid = threadIdx.x;
  const int b = blockIdx.y;
  const int n0 = blockIdx.x * 32;
  // stage conv tile (32 ch x 32 pts fp32) + weights
  {
    int ch = tid >> 3, grp = tid & 7;
    float4 v = *(const float4*)(hfull + (size_t)(b * CH + ch) * NN + n0 + grp * 4);
    int p = grp * 4;
    hTc[ch][p + 0] = v.x; hTc[ch][p + 1] = v.y;
    hTc[ch][p + 2] = v.z; hTc[ch][p + 3] = v.w;
  }
  for(int idx = tid; idx < 1024; idx += 256)
    Wl[(idx & 31) * 32 + (idx >> 5)] = cw[layer * 1024 + idx];
  if(tid < 32) Bl[tid] = cbias[layer * 32 + tid];
  const int lane = tid & 63;
  const int w = tid >> 6;
  const int tl = w >> 1;             // n16-tile within block (0,1)
  const int kh = w & 1;              // kk-half (0: kk 0-8, 1: kk 9-17)
  const int row = lane & 15, q = lane >> 4;
  const int n16 = blockIdx.x * 2 + tl;
  const ushort_t* vb = VTF + ((size_t)(b * 512 + n16) * 18 + kh * 9) * 512 + lane * 8;
  const ushort_t* gH = ghi + (size_t)b * 18432 + kh * 9 * 1024 + lane * 8;
  const ushort_t* gL = glo + (size_t)b * 18432 + kh * 9 * 1024 + lane * 8;
  floatx4 a0h = {0.f,0.f,0.f,0.f}, a0l = {0.f,0.f,0.f,0.f};
  floatx4 a1h = {0.f,0.f,0.f,0.f}, a1l = {0.f,0.f,0.f,0.f};
  #pragma unroll
  for(int kk = 0; kk < 9; ++kk){
    short8 Bv  = *(const short8*)(vb + kk * 512);
    short8 Ah0 = *(const short8*)(gH + kk * 1024);
    short8 Ah1 = *(const short8*)(gH + kk * 1024 + 512);
    short8 Al0 = *(const short8*)(gL + kk * 1024);
    short8 Al1 = *(const short8*)(gL + kk * 1024 + 512);
    a0h = __builtin_amdgcn_mfma_f32_16x16x32_bf16(Ah0, Bv, a0h, 0, 0, 0);
    a0l = __builtin_amdgcn_mfma_f32_16x16x32_bf16(Al0, Bv, a0l, 0, 0, 0);
    a1h = __builtin_amdgcn_mfma_f32_16x16x32_bf16(Ah1, Bv, a1h, 0, 0, 0);
    a1l = __builtin_amdgcn_mfma_f32_16x16x32_bf16(Al1, Bv, a1l, 0, 0, 0);
  }
  floatx4 p0 = a0h + a0l;            // channels 0-15 partial (this kk-half)
  floatx4 p1 = a1h + a1l;            // channels 16-31 partial
  // ship the half we don't own; keep the half we do (kh -> channel half kh)
  xch[w][lane] = kh ? p0 : p1;
  __syncthreads();
  floatx4 accF = (kh ? p1 : p0) + xch[tl * 2 + (1 - kh)][lane];
  // conv path from LDS (fp32, per-channel order identical -> bitwise same)
  const int cb = kh * 16 + q * 4;
  const int pt = tl * 16 + row;
  float acc2[4] = { Bl[cb], Bl[cb + 1], Bl[cb + 2], Bl[cb + 3] };
  #pragma unroll
  for(int i = 0; i < CH; ++i){
    float hv = hTc[i][pt];
    float4 wv = *(const float4*)&Wl[i * 32 + cb];
    acc2[0] = fmaf(hv, wv.x, acc2[0]);
    acc2[1] = fmaf(hv, wv.y, acc2[1]);
    acc2[2] = fmaf(hv, wv.z, acc2[2]);
    acc2[3] = fmaf(hv, wv.w, acc2[3]);
  }
  const float sc = 2.0f / 8192.0f;
  if constexpr(!LAST){
    #pragma unroll
    for(int r = 0; r < 4; ++r){
      int c = cb + r;
      float v = gelu_f(accF[r] * sc + acc2[r]);
      size_t idx = (size_t)(b * CH + c) * NN + n0 + pt;
      hout[idx] = v; houtb[idx] = f2b(v);
    }
  } else {
    // MFMA fc1(gelu)+fc2 epilogue: hi/lo limb split; W fragments from global (L2-hot)
    __shared__ ushort_t hHi[32][40];   // pad 40 shorts: odd 16B stride
    __shared__ ushort_t hLo[32][40];
    __shared__ float b1s[128], w2s[128];
    __shared__ float part[2][32];
    {
      ushort_t H[4], L[4];
      #pragma unroll
      for(int r = 0; r < 4; ++r){
        float v = accF[r] * sc + acc2[r];
        H[r] = f2b(v); L[r] = f2b(v - b2f(H[r]));
      }
      uint2 uu;
      uu.x = (unsigned)H[0] | ((unsigned)H[1] << 16);
      uu.y = (unsigned)H[2] | ((unsigned)H[3] << 16);
      *(uint2*)&hHi[pt][cb] = uu;
      uu.x = (unsigned)L[0] | ((unsigned)L[1] << 16);
      uu.y = (unsigned)L[2] | ((unsigned)L[3] << 16);
      *(uint2*)&hLo[pt][cb] = uu;
    }
    if(tid < 128){ b1s[tid] = b1[tid]; w2s[tid] = w2[tid]; }
    __syncthreads();
    const int cl = row;
    short8 Ahi = *(const short8*)&hHi[tl * 16 + cl][q * 8];
    short8 Alo = *(const short8*)&hLo[tl * 16 + cl][q * 8];
    float S0 = 0.f, S1 = 0.f, S2 = 0.f, S3 = 0.f;
    #pragma unroll
    for(int jt2 = 0; jt2 < 4; ++jt2){
      int jt = kh * 4 + jt2;
      short8 Bhi = *(const short8*)(WBg + (jt * 64 + lane) * 8);
      short8 Blo = *(const short8*)(WBg + 4096 + (jt * 64 + lane) * 8);
      floatx4 acc = {0.f, 0.f, 0.f, 0.f};
      acc = __builtin_amdgcn_mfma_f32_16x16x32_bf16(Ahi, Bhi, acc, 0, 0, 0);
      acc = __builtin_amdgcn_mfma_f32_16x16x32_bf16(Alo, Bhi, acc, 0, 0, 0);
      acc = __builtin_amdgcn_mfma_f32_16x16x32_bf16(Ahi, Blo, acc, 0, 0, 0);
      float bv = b1s[jt * 16 + cl], wv = w2s[jt * 16 + cl];
      S0 = fmaf(gelu_f(acc[0] + bv), wv, S0);
      S1 = fmaf(gelu_f(acc[1] + bv), wv, S1);
      S2 = fmaf(gelu_f(acc[2] + bv), wv, S2);
      S3 = fmaf(gelu_f(acc[3] + bv), wv, S3);
    }
    #pragma unroll
    for(int off = 8; off; off >>= 1){
      S0 += __shfl_xor(S0, off, 16);
      S1 += __shfl_xor(S1, off, 16);
      S2 += __shfl_xor(S2, off, 16);
      S3 += __shfl_xor(S3, off, 16);
    }
    if(cl == 0){
      int pb = tl * 16 + q * 4;
      part[kh][pb + 0] = S0;
      part[kh][pb + 1] = S1;
      part[kh][pb + 2] = S2;
      part[kh][pb + 3] = S3;
    }
    __syncthreads();
    if(tid < 32)
      out[(size_t)b * NN + n0 + tid] = part[0][tid] + part[1][tid] + b2[0];
  }
}

// ---------- launch ----------
extern "C" void kernel_launch(void* const* d_in, const int* in_sizes, int n_in,
                              void* d_out, int out_size, void* d_ws, size_t ws_size,
                              hipStream_t stream)
{
  const float* x      = (const float*)d_in[0];
  const float* fc0_w  = (const float*)d_in[1];
  const float* fc0_b  = (const float*)d_in[2];
  const float* spec_w = (const float*)d_in[3];
  const float* conv_w = (const float*)d_in[4];
  const float* conv_b = (const float*)d_in[5];
  const float* fc1_w  = (const float*)d_in[6];
  const float* fc1_b  = (const float*)d_in[7];
  const float* fc2_w  = (const float*)d_in[8];
  const float* fc2_b  = (const float*)d_in[9];
  float* out = (float*)d_out;

  char* w = (char*)d_ws;
  const size_t OFF_PMM  = 0;
  const size_t OFF_WT   = 4096;
  const size_t OFF_AF   = OFF_WT  + 9437184;
  const size_t OFF_VTF  = OFF_AF  + 37748736;
  const size_t OFF_H0   = OFF_VTF + 37748736;
  const size_t OFF_H1   = OFF_H0  + 4194304;
  const size_t OFF_H0B  = OFF_H1  + 4194304;
  const size_t OFF_H1B  = OFF_H0B + 2097152;
  const size_t OFF_XP   = OFF_H1B + 2097152;
  const size_t OFF_GHI  = OFF_XP  + 2359296;
  const size_t OFF_GLO  = OFF_GHI + 147456;
  const size_t OFF_WB   = OFF_GLO + 147456;

  float4* pmm    = (float4*)(w + OFF_PMM);
  float2* wt     = (float2*)(w + OFF_WT);
  ushort_t* AF   = (ushort_t*)(w + OFF_AF);
  ushort_t* VTF  = (ushort_t*)(w + OFF_VTF);
  float* hbuf[2]     = { (float*)(w + OFF_H0), (float*)(w + OFF_H1) };
  ushort_t* hbufb[2] = { (ushort_t*)(w + OFF_H0B), (ushort_t*)(w + OFF_H1B) };
  float* xp      = (float*)(w + OFF_XP);
  ushort_t* ghi  = (ushort_t*)(w + OFF_GHI);
  ushort_t* glo  = (ushort_t*)(w + OFF_GLO);
  ushort_t* WB   = (ushort_t*)(w + OFF_WB);

  hipLaunchKernelGGL(k_pre, dim3(4737), dim3(256), 0, stream, spec_w, wt, x, pmm,
                     fc1_w, WB);
  hipLaunchKernelGGL(k_vbuild, dim3(1024), dim3(256), 0, stream, x, pmm,
                     fc0_w, fc0_b, AF, VTF, hbuf[0], hbufb[0]);

  for(int l = 0; l < 4; ++l){
    int in = l & 1, outb = 1 - in;
    hipLaunchKernelGGL(k_fwd, dim3(18, 8, NB), dim3(256), 0, stream, AF, hbufb[in], xp);
    hipLaunchKernelGGL(k_mixg, dim3(72, NB), dim3(256), 0, stream, xp, wt, ghi, glo, l);
    if(l < 3)
      hipLaunchKernelGGL(k_inv<0>, dim3(256, NB), dim3(256), 0, stream, VTF, ghi, glo,
                         hbuf[in], conv_w, conv_b, hbuf[outb], hbufb[outb], l,
                         fc1_w, fc1_b, fc2_w, fc2_b, out, WB);
    else
      hipLaunchKernelGGL(k_inv<1>, dim3(256, NB), dim3(256), 0, stream, VTF, ghi, glo,
                         hbuf[in], conv_w, conv_b, hbuf[outb], hbufb[outb], l,
                         fc1_w, fc1_b, fc2_w, fc2_b, out, WB);
  }
  (void)in_sizes; (void)n_in; (void)out_size; (void)ws_size;
}

// Round 4
// 223.863 us; speedup vs baseline: 1.6007x; 1.6007x over previous
//
#include <hip/hip_runtime.h>
#include <cmath>

#define NB 4
#define NN 8192
#define CH 32

typedef short short8 __attribute__((ext_vector_type(8)));
typedef float floatx4 __attribute__((ext_vector_type(4)));
typedef unsigned short ushort_t;

// ---------- helpers ----------
__device__ __forceinline__ unsigned short f2b(float f){
  unsigned u = __float_as_uint(f);
  u = u + 0x7FFFu + ((u >> 16) & 1u);   // RNE
  return (unsigned short)(u >> 16);
}
__device__ __forceinline__ float b2f(unsigned short h){
  return __uint_as_float(((unsigned)h) << 16);
}
__device__ __forceinline__ float gelu_f(float v){
  return 0.5f * v * (1.0f + erff(v * 0.70710678118654752440f));
}
// rep-index closed forms (t in [0,552), t = j*24+i)
__device__ __forceinline__ int repk(int t){   // -1 if t is not a representative
  int j = t / 24, i = t - j * 24;
  if(j == 0)  return (i <= 12) ? i : -1;
  if(j <= 11) return 13 + (j - 1) * 24 + i;
  return (i == 12) ? 277 + (j - 12) : -1;
}
__device__ __forceinline__ int partner(int t){
  int j = t / 24, i = t - j * 24;
  return ((23 - j) % 23) * 24 + ((24 - i) % 24);
}
__device__ __forceinline__ int repT(int k){   // inverse of repk over reps
  if(k < 13) return k;
  if(k < 277){ int m = k - 13; return (m / 24 + 1) * 24 + (m % 24); }
  return (k - 277 + 12) * 24 + 12;
}

// ---------- fused: spec_w reorder + minmax partials + fc1_w/conv_w fragment pre-split ----------
__global__ __launch_bounds__(256) void k_pre(const float* __restrict__ spec,
    float2* __restrict__ wt, const float* __restrict__ x, float4* __restrict__ pmm,
    const float* __restrict__ fc1w, ushort_t* __restrict__ WB,
    const float* __restrict__ convw, ushort_t* __restrict__ WA)
{
  const int tid = threadIdx.x;
  if(blockIdx.x < 128){
    int g = blockIdx.x * 256 + tid;           // 32768 threads
    float a = x[(size_t)g * 2], b = x[(size_t)g * 2 + 1];
    float mn0 = a, mx0 = a, mn1 = b, mx1 = b;
    for(int off = 32; off > 0; off >>= 1){
      mn0 = fminf(mn0, __shfl_down(mn0, off));
      mx0 = fmaxf(mx0, __shfl_down(mx0, off));
      mn1 = fminf(mn1, __shfl_down(mn1, off));
      mx1 = fmaxf(mx1, __shfl_down(mx1, off));
    }
    __shared__ float4 wp[4];
    if((tid & 63) == 0) wp[tid >> 6] = make_float4(mn0, mn1, mx0, mx1);
    __syncthreads();
    if(tid == 0){
      float4 r = wp[0];
      for(int i2 = 1; i2 < 4; ++i2){
        float4 v = wp[i2];
        r.x = fminf(r.x, v.x); r.y = fminf(r.y, v.y);
        r.z = fmaxf(r.z, v.z); r.w = fmaxf(r.w, v.w);
      }
      pmm[blockIdx.x] = r;
    }
  } else if(blockIdx.x < 4736){
    int g = (blockIdx.x - 128) * 256 + tid;   // 1,179,648
    int o  = g & 31;
    int i  = (g >> 5) & 31;
    int rest = g >> 10;
    int pq = rest % 144;
    int ls = rest / 144;                      // l*2+sel
    wt[g] = ((const float2*)spec)[(((size_t)(ls * 32 + i) * 32 + o) * 144 + pq)];
  } else {
    // fc1_w [32][128] -> bf16 hi/lo MFMA B-fragments, 8 jj-tiles.
    for(int s = tid; s < 512; s += 256){
      int jt = s >> 6, l = s & 63;
      int c = l & 15, qq = l >> 4;
      #pragma unroll
      for(int e = 0; e < 8; ++e){
        float wv = fc1w[(qq * 8 + e) * 128 + jt * 16 + c];
        ushort_t hi = f2b(wv);
        WB[(jt * 64 + l) * 8 + e] = hi;
        WB[4096 + (jt * 64 + l) * 8 + e] = f2b(wv - b2f(hi));
      }
    }
    // conv_w [4][32][32] * 4096 -> A-fragments, hi/lo limbs, 2 ch-halves.
    // WA[((l*2+limb)*2+half)*512 + lane*8 + e] = limb of conv_w[l][half*16+(lane&15)][(lane>>4)*8+e]*4096
    for(int s = tid; s < 8192; s += 256){
      int l2   = s >> 11;
      int rem  = s & 2047;
      int limb = rem >> 10;
      int rem2 = rem & 1023;
      int half = rem2 >> 9;
      int le   = rem2 & 511;
      int lane = le >> 3, e = le & 7;
      int c = half * 16 + (lane & 15);
      int i = (lane >> 4) * 8 + e;
      float wv = convw[((size_t)l2 * 32 + c) * 32 + i] * 4096.0f;
      ushort_t hi = f2b(wv);
      WA[s] = limb ? f2b(wv - b2f(hi)) : hi;
    }
  }
}

// ---------- build V in MFMA-fragment layouts + fc0 ----------
// AF : forward A-operand.  [b][st=36][ng=256][q=4][srow=16][e=8] shorts
// VTF: inverse B-operand.  [b][n16=512][kk=18][q=4][n15=16][e=8] shorts
// hbB: forward B-operand (n-contraction). [b][half][g=256][q][cl][e]
// hbC: conv B-operand (ch-contraction).   [b][t16=512][q][cl][e]  (hi and lo)
__global__ __launch_bounds__(256) void k_vbuild(const float* __restrict__ x,
    const float4* __restrict__ pmm, const float* __restrict__ fw,
    const float* __restrict__ fb, ushort_t* __restrict__ AF, ushort_t* __restrict__ VTF,
    ushort_t* __restrict__ hbB, ushort_t* __restrict__ hbChi, ushort_t* __restrict__ hbClo)
{
  __shared__ ushort_t lds1[32 * 584];
  __shared__ float4 mmv;
  const int tid = threadIdx.x;
  if(tid < 64){
    float4 a = pmm[tid], c = pmm[tid + 64];
    float mn0 = fminf(a.x, c.x), mn1 = fminf(a.y, c.y);
    float mx0 = fmaxf(a.z, c.z), mx1 = fmaxf(a.w, c.w);
    for(int off = 32; off > 0; off >>= 1){
      mn0 = fminf(mn0, __shfl_down(mn0, off));
      mn1 = fminf(mn1, __shfl_down(mn1, off));
      mx0 = fmaxf(mx0, __shfl_down(mx0, off));
      mx1 = fmaxf(mx1, __shfl_down(mx1, off));
    }
    if(tid == 0) mmv = make_float4(mn0, mn1, mx0, mx1);
  }
  __syncthreads();
  const int nl = tid & 31, part = tid >> 5;
  const int b = blockIdx.x >> 8;
  const int nblk = blockIdx.x & 255;
  const int n = nblk * 32 + nl;
  float mn0 = mmv.x, mn1 = mmv.y, mx0 = mmv.z, mx1 = mmv.w;
  float x0 = x[(size_t)(b * NN + n) * 2]     - mn0;
  float x1 = x[(size_t)(b * NN + n) * 2 + 1] - mn1;
  float sp = x0 * (6.28f / (mx0 - mn0));
  float sq = x1 * (6.28f / (mx1 - mn1));
  float cx, sx, cy, sy;
  sincosf(sp, &sx, &cx);
  sincosf(sq, &sy, &cy);
  int j0 = part * 3;
  int j1 = (j0 + 3 < 23) ? j0 + 3 : 23;
  float ky0 = (j0 < 12) ? (float)j0 : (float)(j0 - 23);
  float cb, sb;
  sincosf(ky0 * sq, &sb, &cb);
  for(int j = j0; j < j1; ++j){
    float ca = 1.0f, sa = 0.0f;   // kx = 0
    #pragma unroll
    for(int i = 0; i < 24; ++i){
      float vr = ca * cb - sa * sb;        //  cos(kx*sp + ky*sq)
      float vi = -(sa * cb + ca * sb);     // -sin(kx*sp + ky*sq)
      int t = j * 24 + i;
      int k = repk(t);
      if(k >= 0){
        lds1[nl * 584 + k]       = f2b(vr);
        lds1[nl * 584 + 288 + k] = f2b(vi);
      }
      float cn = ca * cx - sa * sx;
      float sn = sa * cx + ca * sx;
      if(i == 11) sn = -sn;                // kx 11 -> -12 (conjugate)
      ca = cn; sa = sn;
    }
    float cbn = cb * cy - sb * sy;
    float sbn = sb * cy + cb * sy;
    cb = cbn; sb = sbn;
  }
  __syncthreads();
  // phase-1 emission: VTF (coalesced 16B/lane)
  #pragma unroll
  for(int r = 0; r < 9; ++r){
    int c = tid + 256 * r;                  // [0,2304)
    int t16 = c / 1152;
    int c2 = c - t16 * 1152;
    int kk = c2 >> 6;
    int rem = c2 & 63;
    int q = rem >> 4, n15 = rem & 15;
    short8 v = *(const short8*)(lds1 + (t16 * 16 + n15) * 584 + kk * 32 + q * 8);
    *(short8*)(VTF + ((size_t)((b * 512 + nblk * 2 + t16) * 18 + kk)) * 512
               + (q * 16 + n15) * 8) = v;
  }
  // phase-2 emission: AF via conjugate symmetry from LDS
  #pragma unroll
  for(int r = 0; r < 9; ++r){
    int c = tid + 256 * r;                  // [0,2304)
    int st = c >> 6;
    int rem = c & 63;
    int q = rem >> 4, srow = rem & 15;
    int sg = st * 16 + srow;                // [0,576)
    int s = (sg < 288) ? sg : sg - 288;
    int sinh_ = (sg >= 288);
    int p2 = s / 12, qq = s - p2 * 12;
    int t = p2 * 23 + qq;
    int k = repk(t);
    unsigned short flip = 0;
    if(k < 0){ k = repk(partner(t)); if(sinh_) flip = 0x8000; }
    int col = sinh_ ? 288 + k : k;
    ushort_t tmp[8];
    #pragma unroll
    for(int e = 0; e < 8; ++e)
      tmp[e] = lds1[(q * 8 + e) * 584 + col] ^ flip;
    *(short8*)(AF + ((size_t)((b * 36 + st) * 256 + nblk)) * 512
               + (q * 16 + srow) * 8) = *(short8*)tmp;
  }
  // fused fc0 -> hbB (hi) + hbC (hi/lo)
  #pragma unroll
  for(int rr = 0; rr < 4; ++rr){
    int c2 = part + rr * 8;
    float v = fb[c2] + x0 * fw[c2] + x1 * fw[32 + c2];
    ushort_t hi = f2b(v), lo = f2b(v - b2f(hi));
    int half = c2 >> 4, cl = c2 & 15;
    hbB[(((size_t)(b * 2 + half) * 256 + nblk) * 512) + ((nl >> 3) * 16 + cl) * 8 + (nl & 7)] = hi;
    size_t ca = ((size_t)(b * 512 + nblk * 2 + (nl >> 4))) * 512
              + ((c2 >> 3) * 16 + (nl & 15)) * 8 + (c2 & 7);
    hbChi[ca] = hi; hbClo[ca] = lo;
  }
}

// ---------- forward transform (K-split 8, 2 s-tiles/block): xp[ks][b][576][32] ----------
__global__ __launch_bounds__(256) void k_fwd(const ushort_t* __restrict__ AF,
    const ushort_t* __restrict__ hbB, float* __restrict__ xp)
{
  const int stp = blockIdx.x;      // 18 pairs
  const int ks = blockIdx.y;       // 8
  const int b  = blockIdx.z;
  const int w = threadIdx.x >> 6;
  const int lane = threadIdx.x & 63;
  const int row = lane & 15;
  const int q = lane >> 4;
  const int st0 = stp * 2;
  const size_t abase0 = ((size_t)(b * 36 + st0) * 256) * 512 + (q * 16 + row) * 8;
  const size_t abase1 = abase0 + (size_t)256 * 512;
  const size_t hB0 = ((size_t)(b * 2 + 0) * 256) * 512 + (size_t)lane * 8;
  const size_t hB1 = ((size_t)(b * 2 + 1) * 256) * 512 + (size_t)lane * 8;
  floatx4 aA0 = {0.f,0.f,0.f,0.f}, aA1 = {0.f,0.f,0.f,0.f};
  floatx4 aB0 = {0.f,0.f,0.f,0.f}, aB1 = {0.f,0.f,0.f,0.f};
  #pragma unroll
  for(int kk = 0; kk < 8; ++kk){
    int g = ks * 32 + w * 8 + kk;
    short8 A0 = *(const short8*)(AF + abase0 + (size_t)g * 512);
    short8 A1 = *(const short8*)(AF + abase1 + (size_t)g * 512);
    short8 B0 = *(const short8*)(hbB + hB0 + (size_t)g * 512);
    short8 B1 = *(const short8*)(hbB + hB1 + (size_t)g * 512);
    aA0 = __builtin_amdgcn_mfma_f32_16x16x32_bf16(A0, B0, aA0, 0, 0, 0);
    aA1 = __builtin_amdgcn_mfma_f32_16x16x32_bf16(A0, B1, aA1, 0, 0, 0);
    aB0 = __builtin_amdgcn_mfma_f32_16x16x32_bf16(A1, B0, aB0, 0, 0, 0);
    aB1 = __builtin_amdgcn_mfma_f32_16x16x32_bf16(A1, B1, aB1, 0, 0, 0);
  }
  __shared__ float red[4 * 512];
  const int e = threadIdx.x;
  #pragma unroll
  for(int r = 0; r < 4; ++r){
    int rrow = q * 4 + r;
    red[w * 512 + rrow * 32 + row]      = aA0[r];
    red[w * 512 + rrow * 32 + 16 + row] = aA1[r];
  }
  __syncthreads();
  {
    float v0 = red[e] + red[512 + e] + red[1024 + e] + red[1536 + e];
    float v1 = red[e + 256] + red[512 + e + 256] + red[1024 + e + 256] + red[1536 + e + 256];
    size_t base = ((size_t)(ks * NB + b) * 576 + st0 * 16) * 32;
    xp[base + e] = v0;
    xp[base + e + 256] = v1;
  }
  __syncthreads();
  #pragma unroll
  for(int r = 0; r < 4; ++r){
    int rrow = q * 4 + r;
    red[w * 512 + rrow * 32 + row]      = aB0[r];
    red[w * 512 + rrow * 32 + 16 + row] = aB1[r];
  }
  __syncthreads();
  {
    float v0 = red[e] + red[512 + e] + red[1024 + e] + red[1536 + e];
    float v1 = red[e + 256] + red[512 + e + 256] + red[1024 + e + 256] + red[1536 + e + 256];
    size_t base = ((size_t)(ks * NB + b) * 576 + (st0 + 1) * 16) * 32;
    xp[base + e] = v0;
    xp[base + e + 256] = v1;
  }
}

// ---------- fused mix + fold -> ghi/glo (wave per rep, 4 reps/block) ----------
__global__ __launch_bounds__(256) void k_mixg(const float* __restrict__ xp,
    const float2* __restrict__ wt, ushort_t* __restrict__ ghi, ushort_t* __restrict__ glo,
    int layer)
{
  const int w = threadIdx.x >> 6;
  const int lane = threadIdx.x & 63;
  const int k = blockIdx.x * 4 + w;    // 288 reps
  const int b = blockIdx.y;
  const int t = repT(k);
  const int j = t / 24, i = t - j * 24;
  const int u = partner(t);
  const bool unpaired = (i == 12) || (u == t);
  const int idxT = (t < 288) ? t : 575 - t;  const bool cfT = (t >= 288);
  const int idxU = (u < 288) ? u : 575 - u;  const bool cfU = (u >= 288);
  __shared__ float Xs[4][2][64];
  const int o = lane & 31, half = lane >> 5;
  #pragma unroll
  for(int m = 0; m < 2; ++m){
    int idx = m ? idxU : idxT;
    int rrow = half ? 288 + idx : idx;
    float s = 0.f;
    #pragma unroll
    for(int ks = 0; ks < 8; ++ks)
      s += xp[((size_t)(ks * NB + b) * 576 + rrow) * 32 + o];
    Xs[w][m][half * 32 + o] = s;
  }
  __syncthreads();
  float Fr[2], Fi[2];
  #pragma unroll
  for(int m = 0; m < 2; ++m){
    int idx = m ? idxU : idxT;
    int p2 = idx / 12, qq = idx - p2 * 12;
    int sel = (p2 < 12) ? 0 : 1;
    int pq = (p2 % 12) * 12 + qq;
    const float2* wb = wt + ((size_t)((layer * 2 + sel) * 144 + pq)) * 1024;
    int i0 = half * 16;
    float fr = 0.f, fi = 0.f;
    #pragma unroll
    for(int ii = 0; ii < 16; ++ii){
      int i2 = i0 + ii;
      float xr = Xs[w][m][i2], xi = Xs[w][m][32 + i2];
      float2 wv = wb[i2 * 32 + o];
      fr += xr * wv.x - xi * wv.y;
      fi += xr * wv.y + xi * wv.x;
    }
    fr += __shfl_down(fr, 32);
    fi += __shfl_down(fi, 32);
    Fr[m] = fr; Fi[m] = fi;       // valid in lanes 0..31
  }
  const int c = lane & 31;
  const int srcT = cfT ? 31 - c : c;
  const int srcU = cfU ? 31 - c : c;
  float fax = __shfl(Fr[0], srcT);
  float fay = __shfl(Fi[0], srcT);
  float fbx = __shfl(Fr[1], srcU);
  float fby = __shfl(Fi[1], srcU);
  if(lane < 32){
    float gr = fax;
    float gi = cfT ? -fay : fay;
    if(!unpaired){
      gr += fbx;
      gi -= (cfU ? -fby : fby);
    }
    unsigned short hr = f2b(gr); float lr = gr - b2f(hr);
    unsigned short hi2 = f2b(gi); float li = gi - b2f(hi2);
    size_t base = (size_t)(b * CH + c) * 576;
    ghi[base + k] = hr;          ghi[base + 288 + k] = hi2;
    glo[base + k] = f2b(lr);     glo[base + 288 + k] = f2b(li);
  }
}

// ---------- inverse transform + MFMA-folded 1x1 conv (+gelu | +MFMA fc1/fc2) ----------
// 512 thr, 64 points/block, grid (128,NB)=512 blocks -> 2 blocks/CU (LDS 74.8 KB).
// wave (tl 0..3, hh 0..1): tile tl (16 pts), ch-half hh, ALL 18 kk + 3 conv MFMA.
// No cross-wave exchange, no main-loop barrier. Spectral order identical to R0.
template<int LAST>
__global__ __launch_bounds__(512, 4) void k_inv(const ushort_t* __restrict__ VTF,
    const ushort_t* __restrict__ ghi, const ushort_t* __restrict__ glo,
    const float* __restrict__ cbias, int layer,
    const ushort_t* __restrict__ hbCi_hi, const ushort_t* __restrict__ hbCi_lo,
    ushort_t* __restrict__ hbBo, ushort_t* __restrict__ hbCo_hi,
    ushort_t* __restrict__ hbCo_lo,
    const float* __restrict__ b1, const float* __restrict__ w2,
    const float* __restrict__ b2, float* __restrict__ out,
    const ushort_t* __restrict__ WBg, const ushort_t* __restrict__ WA)
{
  __shared__ ushort_t GH[32][584];   // stride 584 shorts: conflict-minimal ds_read_b128
  __shared__ ushort_t GL[32][584];
  const int tid = threadIdx.x;
  const int b = blockIdx.y;
  const int bx = blockIdx.x;
  // stage G (coalesced: 32 ch x 576 shorts, hi and lo)
  for(int idx = tid; idx < 2304; idx += 512){
    int ch = idx / 72, g8 = (idx - ch * 72) * 8;
    size_t src = (size_t)(b * CH + ch) * 576 + g8;
    *(short8*)&GH[ch][g8] = *(const short8*)(ghi + src);
    *(short8*)&GL[ch][g8] = *(const short8*)(glo + src);
  }
  __syncthreads();
  const int lane = tid & 63;
  const int w = tid >> 6;
  const int tl = w >> 1;             // point tile 0..3
  const int hh = w & 1;              // channel half
  const int row = lane & 15, q = lane >> 4;
  const int t16 = bx * 4 + tl;
  const ushort_t* vb = VTF + ((size_t)(b * 512 + t16) * 18) * 512 + lane * 8;
  const int gr = hh * 16 + row, ko = q * 8;
  floatx4 ah = {0.f,0.f,0.f,0.f}, al = {0.f,0.f,0.f,0.f};
  #pragma unroll
  for(int kk = 0; kk < 18; ++kk){
    short8 Bv = *(const short8*)(vb + (size_t)kk * 512);
    short8 Ah = *(const short8*)&GH[gr][ko + kk * 32];
    short8 Al = *(const short8*)&GL[gr][ko + kk * 32];
    ah = __builtin_amdgcn_mfma_f32_16x16x32_bf16(Ah, Bv, ah, 0, 0, 0);
    al = __builtin_amdgcn_mfma_f32_16x16x32_bf16(Al, Bv, al, 0, 0, 0);
  }
  // conv fold: A = conv_w*4096 (hi/lo limbs), B = h channel-K fragments (hi/lo)
  {
    short8 Whi = *(const short8*)(WA + ((size_t)((layer * 2 + 0) * 2 + hh)) * 512 + lane * 8);
    short8 Wlo = *(const short8*)(WA + ((size_t)((layer * 2 + 1) * 2 + hh)) * 512 + lane * 8);
    short8 Bhi = *(const short8*)(hbCi_hi + ((size_t)(b * 512 + t16)) * 512 + lane * 8);
    short8 Blo = *(const short8*)(hbCi_lo + ((size_t)(b * 512 + t16)) * 512 + lane * 8);
    ah = __builtin_amdgcn_mfma_f32_16x16x32_bf16(Whi, Bhi, ah, 0, 0, 0);
    al = __builtin_amdgcn_mfma_f32_16x16x32_bf16(Wlo, Bhi, al, 0, 0, 0);
    ah = __builtin_amdgcn_mfma_f32_16x16x32_bf16(Whi, Blo, ah, 0, 0, 0);
  }
  floatx4 accF = ah + al;
  const float sc = 2.0f / 8192.0f;
  float cb[4];
  #pragma unroll
  for(int r = 0; r < 4; ++r) cb[r] = cbias[layer * 32 + hh * 16 + q * 4 + r];
  if constexpr(!LAST){
    const int n = bx * 64 + tl * 16 + row;
    const int g = n >> 5, qb = (n >> 3) & 3, e2 = n & 7;
    #pragma unroll
    for(int r = 0; r < 4; ++r){
      int c = hh * 16 + q * 4 + r;
      float v = gelu_f(accF[r] * sc + cb[r]);
      ushort_t hi = f2b(v), lo = f2b(v - b2f(hi));
      hbBo[(((size_t)(b * 2 + hh) * 256 + g) * 512) + (qb * 16 + (q * 4 + r)) * 8 + e2] = hi;
      size_t ca = ((size_t)(b * 512 + t16)) * 512 + ((c >> 3) * 16 + row) * 8 + (c & 7);
      hbCo_hi[ca] = hi; hbCo_lo[ca] = lo;
    }
  } else {
    // MFMA fc1(gelu)+fc2 epilogue: hi/lo limb split; W fragments from global (L2-hot)
    __shared__ ushort_t hHi[64][36];   // pad 36: conflict-spread column reads
    __shared__ ushort_t hLo[64][36];
    __shared__ float part[2][64];
    {
      ushort_t H[4], L[4];
      #pragma unroll
      for(int r = 0; r < 4; ++r){
        float v = accF[r] * sc + cb[r];
        H[r] = f2b(v); L[r] = f2b(v - b2f(H[r]));
      }
      uint2 uu;
      uu.x = (unsigned)H[0] | ((unsigned)H[1] << 16);
      uu.y = (unsigned)H[2] | ((unsigned)H[3] << 16);
      *(uint2*)&hHi[tl * 16 + row][hh * 16 + q * 4] = uu;
      uu.x = (unsigned)L[0] | ((unsigned)L[1] << 16);
      uu.y = (unsigned)L[2] | ((unsigned)L[3] << 16);
      *(uint2*)&hLo[tl * 16 + row][hh * 16 + q * 4] = uu;
    }
    __syncthreads();
    const int cl = row;
    short8 Ahi = *(const short8*)&hHi[tl * 16 + cl][q * 8];
    short8 Alo = *(const short8*)&hLo[tl * 16 + cl][q * 8];
    float S0 = 0.f, S1 = 0.f, S2 = 0.f, S3 = 0.f;
    #pragma unroll
    for(int jt2 = 0; jt2 < 4; ++jt2){
      int jt = hh * 4 + jt2;
      short8 Bhi = *(const short8*)(WBg + (jt * 64 + lane) * 8);
      short8 Blo = *(const short8*)(WBg + 4096 + (jt * 64 + lane) * 8);
      floatx4 acc = {0.f, 0.f, 0.f, 0.f};
      acc = __builtin_amdgcn_mfma_f32_16x16x32_bf16(Ahi, Bhi, acc, 0, 0, 0);
      acc = __builtin_amdgcn_mfma_f32_16x16x32_bf16(Alo, Bhi, acc, 0, 0, 0);
      acc = __builtin_amdgcn_mfma_f32_16x16x32_bf16(Ahi, Blo, acc, 0, 0, 0);
      float bv = b1[jt * 16 + cl], wv = w2[jt * 16 + cl];
      S0 = fmaf(gelu_f(acc[0] + bv), wv, S0);
      S1 = fmaf(gelu_f(acc[1] + bv), wv, S1);
      S2 = fmaf(gelu_f(acc[2] + bv), wv, S2);
      S3 = fmaf(gelu_f(acc[3] + bv), wv, S3);
    }
    #pragma unroll
    for(int off = 8; off; off >>= 1){
      S0 += __shfl_xor(S0, off, 16);
      S1 += __shfl_xor(S1, off, 16);
      S2 += __shfl_xor(S2, off, 16);
      S3 += __shfl_xor(S3, off, 16);
    }
    if(cl == 0){
      int pb = tl * 16 + q * 4;
      part[hh][pb + 0] = S0;
      part[hh][pb + 1] = S1;
      part[hh][pb + 2] = S2;
      part[hh][pb + 3] = S3;
    }
    __syncthreads();
    if(tid < 64)
      out[(size_t)b * NN + bx * 64 + tid] = part[0][tid] + part[1][tid] + b2[0];
  }
}

// ---------- launch ----------
extern "C" void kernel_launch(void* const* d_in, const int* in_sizes, int n_in,
                              void* d_out, int out_size, void* d_ws, size_t ws_size,
                              hipStream_t stream)
{
  const float* x      = (const float*)d_in[0];
  const float* fc0_w  = (const float*)d_in[1];
  const float* fc0_b  = (const float*)d_in[2];
  const float* spec_w = (const float*)d_in[3];
  const float* conv_w = (const float*)d_in[4];
  const float* conv_b = (const float*)d_in[5];
  const float* fc1_w  = (const float*)d_in[6];
  const float* fc1_b  = (const float*)d_in[7];
  const float* fc2_w  = (const float*)d_in[8];
  const float* fc2_b  = (const float*)d_in[9];
  float* out = (float*)d_out;

  char* w = (char*)d_ws;
  const size_t OFF_PMM  = 0;
  const size_t OFF_WT   = 4096;
  const size_t OFF_AF   = OFF_WT  + 9437184;
  const size_t OFF_VTF  = OFF_AF  + 37748736;
  const size_t OFF_HB0  = OFF_VTF + 37748736;   // hbB hi, ping
  const size_t OFF_HB1  = OFF_HB0 + 2097152;
  const size_t OFF_HC0  = OFF_HB1 + 2097152;    // hbC hi, ping
  const size_t OFF_HC1  = OFF_HC0 + 2097152;
  const size_t OFF_HL0  = OFF_HC1 + 2097152;    // hbC lo, ping
  const size_t OFF_HL1  = OFF_HL0 + 2097152;
  const size_t OFF_XP   = OFF_HL1 + 2097152;
  const size_t OFF_GHI  = OFF_XP  + 2359296;
  const size_t OFF_GLO  = OFF_GHI + 147456;
  const size_t OFF_WB   = OFF_GLO + 147456;
  const size_t OFF_WA   = OFF_WB  + 16384;

  float4* pmm    = (float4*)(w + OFF_PMM);
  float2* wt     = (float2*)(w + OFF_WT);
  ushort_t* AF   = (ushort_t*)(w + OFF_AF);
  ushort_t* VTF  = (ushort_t*)(w + OFF_VTF);
  ushort_t* hbB[2]  = { (ushort_t*)(w + OFF_HB0), (ushort_t*)(w + OFF_HB1) };
  ushort_t* hbChi[2] = { (ushort_t*)(w + OFF_HC0), (ushort_t*)(w + OFF_HC1) };
  ushort_t* hbClo[2] = { (ushort_t*)(w + OFF_HL0), (ushort_t*)(w + OFF_HL1) };
  float* xp      = (float*)(w + OFF_XP);
  ushort_t* ghi  = (ushort_t*)(w + OFF_GHI);
  ushort_t* glo  = (ushort_t*)(w + OFF_GLO);
  ushort_t* WB   = (ushort_t*)(w + OFF_WB);
  ushort_t* WA   = (ushort_t*)(w + OFF_WA);

  hipLaunchKernelGGL(k_pre, dim3(4737), dim3(256), 0, stream, spec_w, wt, x, pmm,
                     fc1_w, WB, conv_w, WA);
  hipLaunchKernelGGL(k_vbuild, dim3(1024), dim3(256), 0, stream, x, pmm,
                     fc0_w, fc0_b, AF, VTF, hbB[0], hbChi[0], hbClo[0]);

  for(int l = 0; l < 4; ++l){
    int in = l & 1, outb = 1 - in;
    hipLaunchKernelGGL(k_fwd, dim3(18, 8, NB), dim3(256), 0, stream, AF, hbB[in], xp);
    hipLaunchKernelGGL(k_mixg, dim3(72, NB), dim3(256), 0, stream, xp, wt, ghi, glo, l);
    if(l < 3)
      hipLaunchKernelGGL(k_inv<0>, dim3(128, NB), dim3(512), 0, stream, VTF, ghi, glo,
                         conv_b, l, hbChi[in], hbClo[in],
                         hbB[outb], hbChi[outb], hbClo[outb],
                         fc1_b, fc2_w, fc2_b, out, WB, WA);
    else
      hipLaunchKernelGGL(k_inv<1>, dim3(128, NB), dim3(512), 0, stream, VTF, ghi, glo,
                         conv_b, l, hbChi[in], hbClo[in],
                         hbB[outb], hbChi[outb], hbClo[outb],
                         fc1_b, fc2_w, fc2_b, out, WB, WA);
  }
  (void)in_sizes; (void)n_in; (void)out_size; (void)ws_size;
}

// Round 5
// 221.526 us; speedup vs baseline: 1.6176x; 1.0106x over previous
//
#include <hip/hip_runtime.h>
#include <cmath>

#define NB 4
#define NN 8192
#define CH 32

typedef short short8 __attribute__((ext_vector_type(8)));
typedef float floatx4 __attribute__((ext_vector_type(4)));
typedef unsigned short ushort_t;

// ---------- helpers ----------
__device__ __forceinline__ unsigned short f2b(float f){
  unsigned u = __float_as_uint(f);
  u = u + 0x7FFFu + ((u >> 16) & 1u);   // RNE
  return (unsigned short)(u >> 16);
}
__device__ __forceinline__ float b2f(unsigned short h){
  return __uint_as_float(((unsigned)h) << 16);
}
__device__ __forceinline__ float gelu_f(float v){
  return 0.5f * v * (1.0f + erff(v * 0.70710678118654752440f));
}
// rep-index closed forms (t in [0,552), t = j*24+i)
__device__ __forceinline__ int repk(int t){   // -1 if t is not a representative
  int j = t / 24, i = t - j * 24;
  if(j == 0)  return (i <= 12) ? i : -1;
  if(j <= 11) return 13 + (j - 1) * 24 + i;
  return (i == 12) ? 277 + (j - 12) : -1;
}
__device__ __forceinline__ int partner(int t){
  int j = t / 24, i = t - j * 24;
  return ((23 - j) % 23) * 24 + ((24 - i) % 24);
}
__device__ __forceinline__ int repT(int k){   // inverse of repk over reps
  if(k < 13) return k;
  if(k < 277){ int m = k - 13; return (m / 24 + 1) * 24 + (m % 24); }
  return (k - 277 + 12) * 24 + 12;
}

// ---------- fused: spec_w reorder + minmax partials + fc1_w/conv_w fragment pre-split ----------
__global__ __launch_bounds__(256) void k_pre(const float* __restrict__ spec,
    float2* __restrict__ wt, const float* __restrict__ x, float4* __restrict__ pmm,
    const float* __restrict__ fc1w, ushort_t* __restrict__ WB,
    const float* __restrict__ convw, ushort_t* __restrict__ WA)
{
  const int tid = threadIdx.x;
  if(blockIdx.x < 128){
    int g = blockIdx.x * 256 + tid;           // 32768 threads
    float a = x[(size_t)g * 2], b = x[(size_t)g * 2 + 1];
    float mn0 = a, mx0 = a, mn1 = b, mx1 = b;
    for(int off = 32; off > 0; off >>= 1){
      mn0 = fminf(mn0, __shfl_down(mn0, off));
      mx0 = fmaxf(mx0, __shfl_down(mx0, off));
      mn1 = fminf(mn1, __shfl_down(mn1, off));
      mx1 = fmaxf(mx1, __shfl_down(mx1, off));
    }
    __shared__ float4 wp[4];
    if((tid & 63) == 0) wp[tid >> 6] = make_float4(mn0, mn1, mx0, mx1);
    __syncthreads();
    if(tid == 0){
      float4 r = wp[0];
      for(int i2 = 1; i2 < 4; ++i2){
        float4 v = wp[i2];
        r.x = fminf(r.x, v.x); r.y = fminf(r.y, v.y);
        r.z = fmaxf(r.z, v.z); r.w = fmaxf(r.w, v.w);
      }
      pmm[blockIdx.x] = r;
    }
  } else if(blockIdx.x < 4736){
    int g = (blockIdx.x - 128) * 256 + tid;   // 1,179,648
    int o  = g & 31;
    int i  = (g >> 5) & 31;
    int rest = g >> 10;
    int pq = rest % 144;
    int ls = rest / 144;                      // l*2+sel
    wt[g] = ((const float2*)spec)[(((size_t)(ls * 32 + i) * 32 + o) * 144 + pq)];
  } else {
    // fc1_w [32][128] -> bf16 hi/lo MFMA B-fragments, 8 jj-tiles.
    for(int s = tid; s < 512; s += 256){
      int jt = s >> 6, l = s & 63;
      int c = l & 15, qq = l >> 4;
      #pragma unroll
      for(int e = 0; e < 8; ++e){
        float wv = fc1w[(qq * 8 + e) * 128 + jt * 16 + c];
        ushort_t hi = f2b(wv);
        WB[(jt * 64 + l) * 8 + e] = hi;
        WB[4096 + (jt * 64 + l) * 8 + e] = f2b(wv - b2f(hi));
      }
    }
    // conv_w [4][32][32] * 4096 -> A-fragments, hi/lo limbs, 2 ch-halves.
    for(int s = tid; s < 8192; s += 256){
      int l2   = s >> 11;
      int rem  = s & 2047;
      int limb = rem >> 10;
      int rem2 = rem & 1023;
      int half = rem2 >> 9;
      int le   = rem2 & 511;
      int lane = le >> 3, e = le & 7;
      int c = half * 16 + (lane & 15);
      int i = (lane >> 4) * 8 + e;
      float wv = convw[((size_t)l2 * 32 + c) * 32 + i] * 4096.0f;
      ushort_t hi = f2b(wv);
      WA[s] = limb ? f2b(wv - b2f(hi)) : hi;
    }
  }
}

// ---------- build V in MFMA-fragment layouts + fc0 ----------
// AF : forward A-operand.  [b][st=36][ng=256][q=4][srow=16][e=8] shorts
// VTF: inverse B-operand.  [b][n16=512][kk=18][q=4][n15=16][e=8] shorts
// hbB: forward B-operand (n-contraction). [b][half][g=256][q][cl][e]
// hbC: conv B-operand (ch-contraction).   [b][t16=512][q][cl][e]  (hi and lo)
__global__ __launch_bounds__(256) void k_vbuild(const float* __restrict__ x,
    const float4* __restrict__ pmm, const float* __restrict__ fw,
    const float* __restrict__ fb, ushort_t* __restrict__ AF, ushort_t* __restrict__ VTF,
    ushort_t* __restrict__ hbB, ushort_t* __restrict__ hbChi, ushort_t* __restrict__ hbClo)
{
  __shared__ ushort_t lds1[32 * 584];
  __shared__ float4 mmv;
  const int tid = threadIdx.x;
  if(tid < 64){
    float4 a = pmm[tid], c = pmm[tid + 64];
    float mn0 = fminf(a.x, c.x), mn1 = fminf(a.y, c.y);
    float mx0 = fmaxf(a.z, c.z), mx1 = fmaxf(a.w, c.w);
    for(int off = 32; off > 0; off >>= 1){
      mn0 = fminf(mn0, __shfl_down(mn0, off));
      mn1 = fminf(mn1, __shfl_down(mn1, off));
      mx0 = fmaxf(mx0, __shfl_down(mx0, off));
      mx1 = fmaxf(mx1, __shfl_down(mx1, off));
    }
    if(tid == 0) mmv = make_float4(mn0, mn1, mx0, mx1);
  }
  __syncthreads();
  const int nl = tid & 31, part = tid >> 5;
  const int b = blockIdx.x >> 8;
  const int nblk = blockIdx.x & 255;
  const int n = nblk * 32 + nl;
  float mn0 = mmv.x, mn1 = mmv.y, mx0 = mmv.z, mx1 = mmv.w;
  float x0 = x[(size_t)(b * NN + n) * 2]     - mn0;
  float x1 = x[(size_t)(b * NN + n) * 2 + 1] - mn1;
  float sp = x0 * (6.28f / (mx0 - mn0));
  float sq = x1 * (6.28f / (mx1 - mn1));
  float cx, sx, cy, sy;
  sincosf(sp, &sx, &cx);
  sincosf(sq, &sy, &cy);
  int j0 = part * 3;
  int j1 = (j0 + 3 < 23) ? j0 + 3 : 23;
  float ky0 = (j0 < 12) ? (float)j0 : (float)(j0 - 23);
  float cb, sb;
  sincosf(ky0 * sq, &sb, &cb);
  for(int j = j0; j < j1; ++j){
    float ca = 1.0f, sa = 0.0f;   // kx = 0
    #pragma unroll
    for(int i = 0; i < 24; ++i){
      float vr = ca * cb - sa * sb;        //  cos(kx*sp + ky*sq)
      float vi = -(sa * cb + ca * sb);     // -sin(kx*sp + ky*sq)
      int t = j * 24 + i;
      int k = repk(t);
      if(k >= 0){
        lds1[nl * 584 + k]       = f2b(vr);
        lds1[nl * 584 + 288 + k] = f2b(vi);
      }
      float cn = ca * cx - sa * sx;
      float sn = sa * cx + ca * sx;
      if(i == 11) sn = -sn;                // kx 11 -> -12 (conjugate)
      ca = cn; sa = sn;
    }
    float cbn = cb * cy - sb * sy;
    float sbn = sb * cy + cb * sy;
    cb = cbn; sb = sbn;
  }
  __syncthreads();
  // phase-1 emission: VTF (coalesced 16B/lane)
  #pragma unroll
  for(int r = 0; r < 9; ++r){
    int c = tid + 256 * r;                  // [0,2304)
    int t16 = c / 1152;
    int c2 = c - t16 * 1152;
    int kk = c2 >> 6;
    int rem = c2 & 63;
    int q = rem >> 4, n15 = rem & 15;
    short8 v = *(const short8*)(lds1 + (t16 * 16 + n15) * 584 + kk * 32 + q * 8);
    *(short8*)(VTF + ((size_t)((b * 512 + nblk * 2 + t16) * 18 + kk)) * 512
               + (q * 16 + n15) * 8) = v;
  }
  // phase-2 emission: AF via conjugate symmetry from LDS
  #pragma unroll
  for(int r = 0; r < 9; ++r){
    int c = tid + 256 * r;                  // [0,2304)
    int st = c >> 6;
    int rem = c & 63;
    int q = rem >> 4, srow = rem & 15;
    int sg = st * 16 + srow;                // [0,576)
    int s = (sg < 288) ? sg : sg - 288;
    int sinh_ = (sg >= 288);
    int p2 = s / 12, qq = s - p2 * 12;
    int t = p2 * 23 + qq;
    int k = repk(t);
    unsigned short flip = 0;
    if(k < 0){ k = repk(partner(t)); if(sinh_) flip = 0x8000; }
    int col = sinh_ ? 288 + k : k;
    ushort_t tmp[8];
    #pragma unroll
    for(int e = 0; e < 8; ++e)
      tmp[e] = lds1[(q * 8 + e) * 584 + col] ^ flip;
    *(short8*)(AF + ((size_t)((b * 36 + st) * 256 + nblk)) * 512
               + (q * 16 + srow) * 8) = *(short8*)tmp;
  }
  // fused fc0 -> hbB (hi) + hbC (hi/lo)
  #pragma unroll
  for(int rr = 0; rr < 4; ++rr){
    int c2 = part + rr * 8;
    float v = fb[c2] + x0 * fw[c2] + x1 * fw[32 + c2];
    ushort_t hi = f2b(v), lo = f2b(v - b2f(hi));
    int half = c2 >> 4, cl = c2 & 15;
    hbB[(((size_t)(b * 2 + half) * 256 + nblk) * 512) + ((nl >> 3) * 16 + cl) * 8 + (nl & 7)] = hi;
    size_t ca = ((size_t)(b * 512 + nblk * 2 + (nl >> 4))) * 512
              + ((c2 >> 3) * 16 + (nl & 15)) * 8 + (c2 & 7);
    hbChi[ca] = hi; hbClo[ca] = lo;
  }
}

// ---------- forward transform (K-split 16, 2 s-tiles/block): xp[ks][b][576][32] ----------
__global__ __launch_bounds__(256) void k_fwd(const ushort_t* __restrict__ AF,
    const ushort_t* __restrict__ hbB, float* __restrict__ xp)
{
  const int stp = blockIdx.x;      // 18 pairs
  const int ks = blockIdx.y;       // 16
  const int b  = blockIdx.z;
  const int w = threadIdx.x >> 6;
  const int lane = threadIdx.x & 63;
  const int row = lane & 15;
  const int q = lane >> 4;
  const int st0 = stp * 2;
  const size_t abase0 = ((size_t)(b * 36 + st0) * 256) * 512 + (q * 16 + row) * 8;
  const size_t abase1 = abase0 + (size_t)256 * 512;
  const size_t hB0 = ((size_t)(b * 2 + 0) * 256) * 512 + (size_t)lane * 8;
  const size_t hB1 = ((size_t)(b * 2 + 1) * 256) * 512 + (size_t)lane * 8;
  floatx4 aA0 = {0.f,0.f,0.f,0.f}, aA1 = {0.f,0.f,0.f,0.f};
  floatx4 aB0 = {0.f,0.f,0.f,0.f}, aB1 = {0.f,0.f,0.f,0.f};
  #pragma unroll
  for(int kk = 0; kk < 4; ++kk){
    int g = ks * 16 + w * 4 + kk;
    short8 A0 = *(const short8*)(AF + abase0 + (size_t)g * 512);
    short8 A1 = *(const short8*)(AF + abase1 + (size_t)g * 512);
    short8 B0 = *(const short8*)(hbB + hB0 + (size_t)g * 512);
    short8 B1 = *(const short8*)(hbB + hB1 + (size_t)g * 512);
    aA0 = __builtin_amdgcn_mfma_f32_16x16x32_bf16(A0, B0, aA0, 0, 0, 0);
    aA1 = __builtin_amdgcn_mfma_f32_16x16x32_bf16(A0, B1, aA1, 0, 0, 0);
    aB0 = __builtin_amdgcn_mfma_f32_16x16x32_bf16(A1, B0, aB0, 0, 0, 0);
    aB1 = __builtin_amdgcn_mfma_f32_16x16x32_bf16(A1, B1, aB1, 0, 0, 0);
  }
  __shared__ float red[4 * 512];
  const int e = threadIdx.x;
  #pragma unroll
  for(int r = 0; r < 4; ++r){
    int rrow = q * 4 + r;
    red[w * 512 + rrow * 32 + row]      = aA0[r];
    red[w * 512 + rrow * 32 + 16 + row] = aA1[r];
  }
  __syncthreads();
  {
    float v0 = red[e] + red[512 + e] + red[1024 + e] + red[1536 + e];
    float v1 = red[e + 256] + red[512 + e + 256] + red[1024 + e + 256] + red[1536 + e + 256];
    size_t base = ((size_t)(ks * NB + b) * 576 + st0 * 16) * 32;
    xp[base + e] = v0;
    xp[base + e + 256] = v1;
  }
  __syncthreads();
  #pragma unroll
  for(int r = 0; r < 4; ++r){
    int rrow = q * 4 + r;
    red[w * 512 + rrow * 32 + row]      = aB0[r];
    red[w * 512 + rrow * 32 + 16 + row] = aB1[r];
  }
  __syncthreads();
  {
    float v0 = red[e] + red[512 + e] + red[1024 + e] + red[1536 + e];
    float v1 = red[e + 256] + red[512 + e + 256] + red[1024 + e + 256] + red[1536 + e + 256];
    size_t base = ((size_t)(ks * NB + b) * 576 + (st0 + 1) * 16) * 32;
    xp[base + e] = v0;
    xp[base + e + 256] = v1;
  }
}

// ---------- fused mix + fold -> ghi (row-major) + glof (A-fragment layout) ----------
// glof per b: [hh=2][kk=18][q=4][cl=16][e=8] shorts; element (lane,e) of wave hh,
// fragment kk  =  G_lo[hh*16 + (lane&15)][kk*32 + (lane>>4)*8 + e]
__global__ __launch_bounds__(256) void k_mixg(const float* __restrict__ xp,
    const float2* __restrict__ wt, ushort_t* __restrict__ ghi, ushort_t* __restrict__ glof,
    int layer)
{
  const int w = threadIdx.x >> 6;
  const int lane = threadIdx.x & 63;
  const int k = blockIdx.x * 4 + w;    // 288 reps
  const int b = blockIdx.y;
  const int t = repT(k);
  const int j = t / 24, i = t - j * 24;
  const int u = partner(t);
  const bool unpaired = (i == 12) || (u == t);
  const int idxT = (t < 288) ? t : 575 - t;  const bool cfT = (t >= 288);
  const int idxU = (u < 288) ? u : 575 - u;  const bool cfU = (u >= 288);
  __shared__ float Xs[4][2][64];
  const int o = lane & 31, half = lane >> 5;
  #pragma unroll
  for(int m = 0; m < 2; ++m){
    int idx = m ? idxU : idxT;
    int rrow = half ? 288 + idx : idx;
    float s = 0.f;
    #pragma unroll
    for(int ks = 0; ks < 16; ++ks)
      s += xp[((size_t)(ks * NB + b) * 576 + rrow) * 32 + o];
    Xs[w][m][half * 32 + o] = s;
  }
  __syncthreads();
  float Fr[2], Fi[2];
  #pragma unroll
  for(int m = 0; m < 2; ++m){
    int idx = m ? idxU : idxT;
    int p2 = idx / 12, qq = idx - p2 * 12;
    int sel = (p2 < 12) ? 0 : 1;
    int pq = (p2 % 12) * 12 + qq;
    const float2* wb = wt + ((size_t)((layer * 2 + sel) * 144 + pq)) * 1024;
    int i0 = half * 16;
    float fr = 0.f, fi = 0.f;
    #pragma unroll
    for(int ii = 0; ii < 16; ++ii){
      int i2 = i0 + ii;
      float xr = Xs[w][m][i2], xi = Xs[w][m][32 + i2];
      float2 wv = wb[i2 * 32 + o];
      fr += xr * wv.x - xi * wv.y;
      fi += xr * wv.y + xi * wv.x;
    }
    fr += __shfl_down(fr, 32);
    fi += __shfl_down(fi, 32);
    Fr[m] = fr; Fi[m] = fi;       // valid in lanes 0..31
  }
  const int c = lane & 31;
  const int srcT = cfT ? 31 - c : c;
  const int srcU = cfU ? 31 - c : c;
  float fax = __shfl(Fr[0], srcT);
  float fay = __shfl(Fi[0], srcT);
  float fbx = __shfl(Fr[1], srcU);
  float fby = __shfl(Fi[1], srcU);
  if(lane < 32){
    float gr = fax;
    float gi = cfT ? -fay : fay;
    if(!unpaired){
      gr += fbx;
      gi -= (cfU ? -fby : fby);
    }
    unsigned short hr = f2b(gr); float lr = gr - b2f(hr);
    unsigned short hi2 = f2b(gi); float li = gi - b2f(hi2);
    size_t base = (size_t)(b * CH + c) * 576;
    ghi[base + k] = hr;          ghi[base + 288 + k] = hi2;
    // lo limb in A-fragment layout
    int hhc = c >> 4, cl = c & 15;
    int kk1 = k >> 5, q1 = (k >> 3) & 3, e1 = k & 7;
    size_t fb2 = (size_t)(b * 2 + hhc) * 18;
    glof[(fb2 + kk1) * 512 + (q1 * 16 + cl) * 8 + e1]     = f2b(lr);
    glof[(fb2 + 9 + kk1) * 512 + (q1 * 16 + cl) * 8 + e1] = f2b(li);
  }
}

// ---------- inverse transform + MFMA-folded 1x1 conv (+gelu | +MFMA fc1/fc2) ----------
// 512 thr, 64 points/block, grid (128,NB)=512 blocks. LDS 37.4 KB (GH only; GL read
// from global A-fragments, L2-hot) -> 3 blocks/CU @ launch_bounds(512,6).
// wave (tl 0..3, hh 0..1): tile tl (16 pts), ch-half hh, ALL 18 kk + 3 conv MFMA.
template<int LAST>
__global__ __launch_bounds__(512, 6) void k_inv(const ushort_t* __restrict__ VTF,
    const ushort_t* __restrict__ ghi, const ushort_t* __restrict__ glof,
    const float* __restrict__ cbias, int layer,
    const ushort_t* __restrict__ hbCi_hi, const ushort_t* __restrict__ hbCi_lo,
    ushort_t* __restrict__ hbBo, ushort_t* __restrict__ hbCo_hi,
    ushort_t* __restrict__ hbCo_lo,
    const float* __restrict__ b1, const float* __restrict__ w2,
    const float* __restrict__ b2, float* __restrict__ out,
    const ushort_t* __restrict__ WBg, const ushort_t* __restrict__ WA)
{
  __shared__ ushort_t GH[32][584];   // stride 584 shorts: conflict-minimal ds_read_b128
  const int tid = threadIdx.x;
  const int b = blockIdx.y;
  const int bx = blockIdx.x;
  // stage GH (coalesced: 32 ch x 576 shorts)
  for(int idx = tid; idx < 2304; idx += 512){
    int ch = idx / 72, g8 = (idx - ch * 72) * 8;
    if(g8 < 576)
      *(short8*)&GH[ch][g8] = *(const short8*)(ghi + (size_t)(b * CH + ch) * 576 + g8);
  }
  __syncthreads();
  const int lane = tid & 63;
  const int w = tid >> 6;
  const int tl = w >> 1;             // point tile 0..3
  const int hh = w & 1;              // channel half
  const int row = lane & 15, q = lane >> 4;
  const int t16 = bx * 4 + tl;
  const ushort_t* vb = VTF + ((size_t)(b * 512 + t16) * 18) * 512 + lane * 8;
  const ushort_t* gl = glof + ((size_t)(b * 2 + hh) * 18) * 512 + lane * 8;
  const int gr = hh * 16 + row, ko = q * 8;
  floatx4 ah = {0.f,0.f,0.f,0.f}, al = {0.f,0.f,0.f,0.f};
  #pragma unroll
  for(int kk = 0; kk < 18; ++kk){
    short8 Bv = *(const short8*)(vb + (size_t)kk * 512);
    short8 Ah = *(const short8*)&GH[gr][ko + kk * 32];
    short8 Al = *(const short8*)(gl + (size_t)kk * 512);
    ah = __builtin_amdgcn_mfma_f32_16x16x32_bf16(Ah, Bv, ah, 0, 0, 0);
    al = __builtin_amdgcn_mfma_f32_16x16x32_bf16(Al, Bv, al, 0, 0, 0);
  }
  // conv fold: A = conv_w*4096 (hi/lo limbs), B = h channel-K fragments (hi/lo)
  {
    short8 Whi = *(const short8*)(WA + ((size_t)((layer * 2 + 0) * 2 + hh)) * 512 + lane * 8);
    short8 Wlo = *(const short8*)(WA + ((size_t)((layer * 2 + 1) * 2 + hh)) * 512 + lane * 8);
    short8 Bhi = *(const short8*)(hbCi_hi + ((size_t)(b * 512 + t16)) * 512 + lane * 8);
    short8 Blo = *(const short8*)(hbCi_lo + ((size_t)(b * 512 + t16)) * 512 + lane * 8);
    ah = __builtin_amdgcn_mfma_f32_16x16x32_bf16(Whi, Bhi, ah, 0, 0, 0);
    al = __builtin_amdgcn_mfma_f32_16x16x32_bf16(Wlo, Bhi, al, 0, 0, 0);
    ah = __builtin_amdgcn_mfma_f32_16x16x32_bf16(Whi, Blo, ah, 0, 0, 0);
  }
  floatx4 accF = ah + al;
  const float sc = 2.0f / 8192.0f;
  float cb[4];
  #pragma unroll
  for(int r = 0; r < 4; ++r) cb[r] = cbias[layer * 32 + hh * 16 + q * 4 + r];
  if constexpr(!LAST){
    const int n = bx * 64 + tl * 16 + row;
    const int g = n >> 5, qb = (n >> 3) & 3, e2 = n & 7;
    #pragma unroll
    for(int r = 0; r < 4; ++r){
      int c = hh * 16 + q * 4 + r;
      float v = gelu_f(accF[r] * sc + cb[r]);
      ushort_t hi = f2b(v), lo = f2b(v - b2f(hi));
      hbBo[(((size_t)(b * 2 + hh) * 256 + g) * 512) + (qb * 16 + (q * 4 + r)) * 8 + e2] = hi;
      size_t ca = ((size_t)(b * 512 + t16)) * 512 + ((c >> 3) * 16 + row) * 8 + (c & 7);
      hbCo_hi[ca] = hi; hbCo_lo[ca] = lo;
    }
  } else {
    // MFMA fc1(gelu)+fc2 epilogue: hi/lo limb split; W fragments from global (L2-hot)
    __shared__ ushort_t hHi[64][36];   // pad 36: conflict-spread column reads
    __shared__ ushort_t hLo[64][36];
    __shared__ float part[2][64];
    {
      ushort_t H[4], L[4];
      #pragma unroll
      for(int r = 0; r < 4; ++r){
        float v = accF[r] * sc + cb[r];
        H[r] = f2b(v); L[r] = f2b(v - b2f(H[r]));
      }
      uint2 uu;
      uu.x = (unsigned)H[0] | ((unsigned)H[1] << 16);
      uu.y = (unsigned)H[2] | ((unsigned)H[3] << 16);
      *(uint2*)&hHi[tl * 16 + row][hh * 16 + q * 4] = uu;
      uu.x = (unsigned)L[0] | ((unsigned)L[1] << 16);
      uu.y = (unsigned)L[2] | ((unsigned)L[3] << 16);
      *(uint2*)&hLo[tl * 16 + row][hh * 16 + q * 4] = uu;
    }
    __syncthreads();
    const int cl = row;
    short8 Ahi = *(const short8*)&hHi[tl * 16 + cl][q * 8];
    short8 Alo = *(const short8*)&hLo[tl * 16 + cl][q * 8];
    float S0 = 0.f, S1 = 0.f, S2 = 0.f, S3 = 0.f;
    #pragma unroll
    for(int jt2 = 0; jt2 < 4; ++jt2){
      int jt = hh * 4 + jt2;
      short8 Bhi = *(const short8*)(WBg + (jt * 64 + lane) * 8);
      short8 Blo = *(const short8*)(WBg + 4096 + (jt * 64 + lane) * 8);
      floatx4 acc = {0.f, 0.f, 0.f, 0.f};
      acc = __builtin_amdgcn_mfma_f32_16x16x32_bf16(Ahi, Bhi, acc, 0, 0, 0);
      acc = __builtin_amdgcn_mfma_f32_16x16x32_bf16(Alo, Bhi, acc, 0, 0, 0);
      acc = __builtin_amdgcn_mfma_f32_16x16x32_bf16(Ahi, Blo, acc, 0, 0, 0);
      float bv = b1[jt * 16 + cl], wv = w2[jt * 16 + cl];
      S0 = fmaf(gelu_f(acc[0] + bv), wv, S0);
      S1 = fmaf(gelu_f(acc[1] + bv), wv, S1);
      S2 = fmaf(gelu_f(acc[2] + bv), wv, S2);
      S3 = fmaf(gelu_f(acc[3] + bv), wv, S3);
    }
    #pragma unroll
    for(int off = 8; off; off >>= 1){
      S0 += __shfl_xor(S0, off, 16);
      S1 += __shfl_xor(S1, off, 16);
      S2 += __shfl_xor(S2, off, 16);
      S3 += __shfl_xor(S3, off, 16);
    }
    if(cl == 0){
      int pb = tl * 16 + q * 4;
      part[hh][pb + 0] = S0;
      part[hh][pb + 1] = S1;
      part[hh][pb + 2] = S2;
      part[hh][pb + 3] = S3;
    }
    __syncthreads();
    if(tid < 64)
      out[(size_t)b * NN + bx * 64 + tid] = part[0][tid] + part[1][tid] + b2[0];
  }
}

// ---------- launch ----------
extern "C" void kernel_launch(void* const* d_in, const int* in_sizes, int n_in,
                              void* d_out, int out_size, void* d_ws, size_t ws_size,
                              hipStream_t stream)
{
  const float* x      = (const float*)d_in[0];
  const float* fc0_w  = (const float*)d_in[1];
  const float* fc0_b  = (const float*)d_in[2];
  const float* spec_w = (const float*)d_in[3];
  const float* conv_w = (const float*)d_in[4];
  const float* conv_b = (const float*)d_in[5];
  const float* fc1_w  = (const float*)d_in[6];
  const float* fc1_b  = (const float*)d_in[7];
  const float* fc2_w  = (const float*)d_in[8];
  const float* fc2_b  = (const float*)d_in[9];
  float* out = (float*)d_out;

  char* w = (char*)d_ws;
  const size_t OFF_PMM  = 0;
  const size_t OFF_WT   = 4096;
  const size_t OFF_AF   = OFF_WT  + 9437184;
  const size_t OFF_VTF  = OFF_AF  + 37748736;
  const size_t OFF_HB0  = OFF_VTF + 37748736;   // hbB hi, ping
  const size_t OFF_HB1  = OFF_HB0 + 2097152;
  const size_t OFF_HC0  = OFF_HB1 + 2097152;    // hbC hi, ping
  const size_t OFF_HC1  = OFF_HC0 + 2097152;
  const size_t OFF_HL0  = OFF_HC1 + 2097152;    // hbC lo, ping
  const size_t OFF_HL1  = OFF_HL0 + 2097152;
  const size_t OFF_XP   = OFF_HL1 + 2097152;
  const size_t OFF_GHI  = OFF_XP  + 4718592;    // xp now 16 K-slices
  const size_t OFF_GLO  = OFF_GHI + 147456;
  const size_t OFF_WB   = OFF_GLO + 147456;
  const size_t OFF_WA   = OFF_WB  + 16384;

  float4* pmm    = (float4*)(w + OFF_PMM);
  float2* wt     = (float2*)(w + OFF_WT);
  ushort_t* AF   = (ushort_t*)(w + OFF_AF);
  ushort_t* VTF  = (ushort_t*)(w + OFF_VTF);
  ushort_t* hbB[2]  = { (ushort_t*)(w + OFF_HB0), (ushort_t*)(w + OFF_HB1) };
  ushort_t* hbChi[2] = { (ushort_t*)(w + OFF_HC0), (ushort_t*)(w + OFF_HC1) };
  ushort_t* hbClo[2] = { (ushort_t*)(w + OFF_HL0), (ushort_t*)(w + OFF_HL1) };
  float* xp      = (float*)(w + OFF_XP);
  ushort_t* ghi  = (ushort_t*)(w + OFF_GHI);
  ushort_t* glof = (ushort_t*)(w + OFF_GLO);
  ushort_t* WB   = (ushort_t*)(w + OFF_WB);
  ushort_t* WA   = (ushort_t*)(w + OFF_WA);

  hipLaunchKernelGGL(k_pre, dim3(4737), dim3(256), 0, stream, spec_w, wt, x, pmm,
                     fc1_w, WB, conv_w, WA);
  hipLaunchKernelGGL(k_vbuild, dim3(1024), dim3(256), 0, stream, x, pmm,
                     fc0_w, fc0_b, AF, VTF, hbB[0], hbChi[0], hbClo[0]);

  for(int l = 0; l < 4; ++l){
    int in = l & 1, outb = 1 - in;
    hipLaunchKernelGGL(k_fwd, dim3(18, 16, NB), dim3(256), 0, stream, AF, hbB[in], xp);
    hipLaunchKernelGGL(k_mixg, dim3(72, NB), dim3(256), 0, stream, xp, wt, ghi, glof, l);
    if(l < 3)
      hipLaunchKernelGGL(k_inv<0>, dim3(128, NB), dim3(512), 0, stream, VTF, ghi, glof,
                         conv_b, l, hbChi[in], hbClo[in],
                         hbB[outb], hbChi[outb], hbClo[outb],
                         fc1_b, fc2_w, fc2_b, out, WB, WA);
    else
      hipLaunchKernelGGL(k_inv<1>, dim3(128, NB), dim3(512), 0, stream, VTF, ghi, glof,
                         conv_b, l, hbChi[in], hbClo[in],
                         hbB[outb], hbChi[outb], hbClo[outb],
                         fc1_b, fc2_w, fc2_b, out, WB, WA);
  }
  (void)in_sizes; (void)n_in; (void)out_size; (void)ws_size;
}